// Round 1
// baseline (6451.754 us; speedup 1.0000x reference)
//
#include <hip/hip_runtime.h>

typedef float f32x4 __attribute__((ext_vector_type(4)));
typedef __bf16 bf16x8 __attribute__((ext_vector_type(8)));
typedef unsigned short u16x8 __attribute__((ext_vector_type(8)));

#define F 128

__device__ __forceinline__ unsigned short bf16_rne(float f) {
  unsigned u = __float_as_uint(f);
  u += 0x7FFFu + ((u >> 16) & 1u);
  return (unsigned short)(u >> 16);
}
__device__ __forceinline__ float bf16f(unsigned short s) {
  return __uint_as_float((unsigned)s << 16);
}

// ---------------------------------------------------------------------------
// split8: read 8 f32, write bf16 hi/lo pairs (and optional f32 copy)
// ---------------------------------------------------------------------------
__global__ void split8_kernel(const float* __restrict__ in, float* __restrict__ fcopy,
                              unsigned short* __restrict__ hi, unsigned short* __restrict__ lo,
                              int n8) {
  int i = blockIdx.x * 256 + threadIdx.x;
  if (i >= n8) return;
  const float4* p = (const float4*)in + 2 * (size_t)i;
  float4 a = p[0], b = p[1];
  float v[8] = {a.x, a.y, a.z, a.w, b.x, b.y, b.z, b.w};
  u16x8 vh, vl;
#pragma unroll
  for (int e = 0; e < 8; ++e) {
    unsigned short x = bf16_rne(v[e]);
    vh[e] = x;
    vl[e] = bf16_rne(v[e] - bf16f(x));
  }
  *(u16x8*)(hi + 8 * (size_t)i) = vh;
  *(u16x8*)(lo + 8 * (size_t)i) = vl;
  if (fcopy) {
    float4* q = (float4*)fcopy + 2 * (size_t)i;
    q[0] = a; q[1] = b;
  }
}

// ---------------------------------------------------------------------------
// prep_w: WcT[t][j][k] = dot(W[t][k][:], w_ih[j][:])  (B^T layout [col][k])
//         WhhT stored [j][k] = w_hh[j][k]  (identity copy), both as bf16 hi/lo
// ---------------------------------------------------------------------------
__global__ void prep_w_kernel(const float* __restrict__ W, const float* __restrict__ w_ih,
                              const float* __restrict__ w_hh,
                              unsigned short* __restrict__ WcT_hi, unsigned short* __restrict__ WcT_lo,
                              unsigned short* __restrict__ Whh_hi, unsigned short* __restrict__ Whh_lo,
                              int L) {
  int idx = blockIdx.x * 256 + threadIdx.x;
  const int per_layer = 384 * 128;
  if (idx < L * per_layer) {
    int t = idx / per_layer;
    int r = idx - t * per_layer;
    int j = r >> 7;      // gate col 0..383
    int k = r & 127;     // k 0..127
    const float* wi = w_ih + (size_t)j * 128;
    const float* wk = W + (size_t)t * 16384 + (size_t)k * 128;
    float acc = 0.f;
#pragma unroll 4
    for (int c = 0; c < 128; ++c) acc = fmaf(wk[c], wi[c], acc);
    unsigned short x = bf16_rne(acc);
    WcT_hi[idx] = x;
    WcT_lo[idx] = bf16_rne(acc - bf16f(x));
  } else if (idx < L * per_layer + per_layer) {
    int r = idx - L * per_layer;
    float v = w_hh[r];
    unsigned short x = bf16_rne(v);
    Whh_hi[r] = x;
    Whh_lo[r] = bf16_rne(v - bf16f(x));
  }
}

// ---------------------------------------------------------------------------
// scatter: s[dst] += h[src] over edges, 32 lanes per edge, f32 HW atomics
// ---------------------------------------------------------------------------
__global__ void scatter_kernel(const float* __restrict__ h, const int* __restrict__ ei,
                               float* __restrict__ s, int E) {
  int t = blockIdx.x * 256 + threadIdx.x;
  int e = t >> 5;
  if (e >= E) return;
  int q = (t & 31) << 2;
  int src = ei[e];
  int dst = ei[E + e];
  float4 v = *(const float4*)(h + (size_t)src * F + q);
  float* p = s + (size_t)dst * F + q;
  unsafeAtomicAdd(p + 0, v.x);
  unsafeAtomicAdd(p + 1, v.y);
  unsafeAtomicAdd(p + 2, v.z);
  unsafeAtomicAdd(p + 3, v.w);
}

// ---------------------------------------------------------------------------
// gemm_gru: per block = 32 rows x all 128 gate cols. 8 waves:
//   wave w: rowtile wr=w>>2 (16 rows), gates g0=(w&3)*32 (2 col-tiles of 16).
// For each (gatetile, part in {r,z,n}): C1 = s@Wc, C2 = h@WhhT, each via
// 3 MFMAs (hi*hi, lo*hi, hi*lo) of 16x16x32 bf16. 12 f32x4 accs per lane.
// Epilogue: GRU gates, in-place h update + fused bf16 hi/lo re-split.
// ---------------------------------------------------------------------------
__global__ __launch_bounds__(512) void gemm_gru_kernel(
    const unsigned short* __restrict__ s_hi, const unsigned short* __restrict__ s_lo,
    const unsigned short* __restrict__ h_hi, const unsigned short* __restrict__ h_lo,
    const unsigned short* __restrict__ BcT_hi, const unsigned short* __restrict__ BcT_lo,
    const unsigned short* __restrict__ BhT_hi, const unsigned short* __restrict__ BhT_lo,
    const float* __restrict__ bih, const float* __restrict__ bhh,
    float* __restrict__ h, unsigned short* __restrict__ h_hi_out,
    unsigned short* __restrict__ h_lo_out, int N) {
  const int w    = threadIdx.x >> 6;
  const int lane = threadIdx.x & 63;
  const int wr   = w >> 2;
  const int g0   = (w & 3) * 32;
  const int lrow = lane & 15;
  const int lk   = (lane >> 4) * 8;
  const int row0 = blockIdx.x * 32 + wr * 16;

  int arow = row0 + lrow;
  int arow_c = arow < N ? arow : N - 1;
  const size_t a_base = (size_t)arow_c * F + lk;

  f32x4 acc[12];
#pragma unroll
  for (int i = 0; i < 12; ++i) acc[i] = (f32x4){0.f, 0.f, 0.f, 0.f};

#pragma unroll 1
  for (int k0 = 0; k0 < 128; k0 += 32) {
    const bf16x8 a_sh = *(const bf16x8*)(s_hi + a_base + k0);
    const bf16x8 a_sl = *(const bf16x8*)(s_lo + a_base + k0);
    const bf16x8 a_hh = *(const bf16x8*)(h_hi + a_base + k0);
    const bf16x8 a_hl = *(const bf16x8*)(h_lo + a_base + k0);
#pragma unroll
    for (int t2 = 0; t2 < 2; ++t2) {
#pragma unroll
      for (int part = 0; part < 3; ++part) {
        const size_t boff = (size_t)(g0 + t2 * 16 + part * 128 + lrow) * 128 + k0 + lk;
        const int ia = (t2 * 3 + part) * 2;
        bf16x8 bh = *(const bf16x8*)(BcT_hi + boff);
        bf16x8 bl = *(const bf16x8*)(BcT_lo + boff);
        acc[ia] = __builtin_amdgcn_mfma_f32_16x16x32_bf16(a_sh, bh, acc[ia], 0, 0, 0);
        acc[ia] = __builtin_amdgcn_mfma_f32_16x16x32_bf16(a_sl, bh, acc[ia], 0, 0, 0);
        acc[ia] = __builtin_amdgcn_mfma_f32_16x16x32_bf16(a_sh, bl, acc[ia], 0, 0, 0);
        bh = *(const bf16x8*)(BhT_hi + boff);
        bl = *(const bf16x8*)(BhT_lo + boff);
        acc[ia + 1] = __builtin_amdgcn_mfma_f32_16x16x32_bf16(a_hh, bh, acc[ia + 1], 0, 0, 0);
        acc[ia + 1] = __builtin_amdgcn_mfma_f32_16x16x32_bf16(a_hl, bh, acc[ia + 1], 0, 0, 0);
        acc[ia + 1] = __builtin_amdgcn_mfma_f32_16x16x32_bf16(a_hh, bl, acc[ia + 1], 0, 0, 0);
      }
    }
  }

  // all K-loop reads of h_hi/h_lo in this block must complete before any wave
  // overwrites them (blocks only touch their own 32 rows -> in-place is safe)
  __syncthreads();

  const int rbase = row0 + (lane >> 4) * 4;
#pragma unroll
  for (int t2 = 0; t2 < 2; ++t2) {
    const int c = g0 + t2 * 16 + lrow;
    const float br  = bih[c] + bhh[c];
    const float bz  = bih[128 + c] + bhh[128 + c];
    const float bni = bih[256 + c];
    const float bnh = bhh[256 + c];
#pragma unroll
    for (int i = 0; i < 4; ++i) {
      const int r = rbase + i;
      if (r < N) {
        const float c1r = acc[(t2 * 3 + 0) * 2 + 0][i], c2r = acc[(t2 * 3 + 0) * 2 + 1][i];
        const float c1z = acc[(t2 * 3 + 1) * 2 + 0][i], c2z = acc[(t2 * 3 + 1) * 2 + 1][i];
        const float c1n = acc[(t2 * 3 + 2) * 2 + 0][i], c2n = acc[(t2 * 3 + 2) * 2 + 1][i];
        const float rr = 1.f / (1.f + __expf(-(c1r + c2r + br)));
        const float zz = 1.f / (1.f + __expf(-(c1z + c2z + bz)));
        const float nn = tanhf(c1n + bni + rr * (c2n + bnh));
        const size_t o = (size_t)r * F + c;
        const float hold = h[o];
        const float hn = (1.f - zz) * nn + zz * hold;
        h[o] = hn;
        const unsigned short x = bf16_rne(hn);
        h_hi_out[o] = x;
        h_lo_out[o] = bf16_rne(hn - bf16f(x));
      }
    }
  }
}

// ---------------------------------------------------------------------------
// final: out[n] = relu(h[n]) . lin_w + lin_b   (one wave per node)
// ---------------------------------------------------------------------------
__global__ void final_kernel(const float* __restrict__ h, const float* __restrict__ lin_w,
                             const float* __restrict__ lin_b, float* __restrict__ out, int N) {
  int n = blockIdx.x * 4 + (threadIdx.x >> 6);
  if (n >= N) return;
  int lane = threadIdx.x & 63;
  float2 v = *(const float2*)(h + (size_t)n * F + lane * 2);
  float2 wv = *(const float2*)(lin_w + lane * 2);
  float sum = fmaxf(v.x, 0.f) * wv.x + fmaxf(v.y, 0.f) * wv.y;
#pragma unroll
  for (int o = 32; o; o >>= 1) sum += __shfl_xor(sum, o, 64);
  if (lane == 0) out[n] = sum + lin_b[0];
}

// ---------------------------------------------------------------------------
extern "C" void kernel_launch(void* const* d_in, const int* in_sizes, int n_in,
                              void* d_out, int out_size, void* d_ws, size_t ws_size,
                              hipStream_t stream) {
  const float* x     = (const float*)d_in[0];
  const int*   ei    = (const int*)d_in[1];
  const float* W     = (const float*)d_in[2];
  const float* w_ih  = (const float*)d_in[3];
  const float* w_hh  = (const float*)d_in[4];
  const float* b_ih  = (const float*)d_in[5];
  const float* b_hh  = (const float*)d_in[6];
  const float* lin_w = (const float*)d_in[7];
  const float* lin_b = (const float*)d_in[8];

  const int N = in_sizes[0] / F;         // 50000
  const int E = in_sizes[1] / 2;         // 640000
  const int L = in_sizes[2] / (F * F);   // 5
  const size_t NF = (size_t)N * F;
  const int PW = 384 * 128;              // per-layer combined-weight elems

  float* h = (float*)d_ws;
  float* s = h + NF;
  unsigned short* h_hi = (unsigned short*)(s + NF);
  unsigned short* h_lo = h_hi + NF;
  unsigned short* s_hi = h_lo + NF;
  unsigned short* s_lo = s_hi + NF;
  unsigned short* WcT_hi = s_lo + NF;
  unsigned short* WcT_lo = WcT_hi + (size_t)L * PW;
  unsigned short* Whh_hi = WcT_lo + (size_t)L * PW;
  unsigned short* Whh_lo = Whh_hi + PW;

  const int n8 = (int)(NF / 8);
  const int split_blocks = (n8 + 255) / 256;
  const int prep_blocks = (L * PW + PW + 255) / 256;
  const int scat_blocks = (E * 32 + 255) / 256;
  const int gemm_blocks = (N + 31) / 32;
  const int final_blocks = (N + 3) / 4;

  // h = x (f32 copy) + hi/lo split; combined weights
  split8_kernel<<<split_blocks, 256, 0, stream>>>(x, h, h_hi, h_lo, n8);
  prep_w_kernel<<<prep_blocks, 256, 0, stream>>>(W, w_ih, w_hh, WcT_hi, WcT_lo,
                                                 Whh_hi, Whh_lo, L);

  for (int t = 0; t < L; ++t) {
    hipMemsetAsync(s, 0, NF * sizeof(float), stream);
    scatter_kernel<<<scat_blocks, 256, 0, stream>>>(h, ei, s, E);
    split8_kernel<<<split_blocks, 256, 0, stream>>>(s, nullptr, s_hi, s_lo, n8);
    gemm_gru_kernel<<<gemm_blocks, 512, 0, stream>>>(
        s_hi, s_lo, h_hi, h_lo,
        WcT_hi + (size_t)t * PW, WcT_lo + (size_t)t * PW, Whh_hi, Whh_lo,
        b_ih, b_hh, h, h_hi, h_lo, N);
  }

  final_kernel<<<final_blocks, 256, 0, stream>>>(h, lin_w, lin_b, (float*)d_out, N);
}

// Round 2
// 1438.312 us; speedup vs baseline: 4.4856x; 4.4856x over previous
//
#include <hip/hip_runtime.h>

typedef float f32x4 __attribute__((ext_vector_type(4)));
typedef __bf16 bf16x8 __attribute__((ext_vector_type(8)));
typedef unsigned short u16x8 __attribute__((ext_vector_type(8)));

#define F 128

__device__ __forceinline__ unsigned short bf16_rne(float f) {
  unsigned u = __float_as_uint(f);
  u += 0x7FFFu + ((u >> 16) & 1u);
  return (unsigned short)(u >> 16);
}
__device__ __forceinline__ float bf16f(unsigned short s) {
  return __uint_as_float((unsigned)s << 16);
}

// ---------------------------------------------------------------------------
// split8: read 8 f32, write bf16 hi/lo pairs (and optional f32 copy)
// ---------------------------------------------------------------------------
__global__ void split8_kernel(const float* __restrict__ in, float* __restrict__ fcopy,
                              unsigned short* __restrict__ hi, unsigned short* __restrict__ lo,
                              int n8) {
  int i = blockIdx.x * 256 + threadIdx.x;
  if (i >= n8) return;
  const float4* p = (const float4*)in + 2 * (size_t)i;
  float4 a = p[0], b = p[1];
  float v[8] = {a.x, a.y, a.z, a.w, b.x, b.y, b.z, b.w};
  u16x8 vh, vl;
#pragma unroll
  for (int e = 0; e < 8; ++e) {
    unsigned short x = bf16_rne(v[e]);
    vh[e] = x;
    vl[e] = bf16_rne(v[e] - bf16f(x));
  }
  *(u16x8*)(hi + 8 * (size_t)i) = vh;
  *(u16x8*)(lo + 8 * (size_t)i) = vl;
  if (fcopy) {
    float4* q = (float4*)fcopy + 2 * (size_t)i;
    q[0] = a; q[1] = b;
  }
}

// ---------------------------------------------------------------------------
// prep_w: WcT[t][j][k] = dot(W[t][k][:], w_ih[j][:])  (B^T layout [col][k])
//         WhhT stored [j][k] = w_hh[j][k]  (identity copy), both as bf16 hi/lo
// ---------------------------------------------------------------------------
__global__ void prep_w_kernel(const float* __restrict__ W, const float* __restrict__ w_ih,
                              const float* __restrict__ w_hh,
                              unsigned short* __restrict__ WcT_hi, unsigned short* __restrict__ WcT_lo,
                              unsigned short* __restrict__ Whh_hi, unsigned short* __restrict__ Whh_lo,
                              int L) {
  int idx = blockIdx.x * 256 + threadIdx.x;
  const int per_layer = 384 * 128;
  if (idx < L * per_layer) {
    int t = idx / per_layer;
    int r = idx - t * per_layer;
    int j = r >> 7;      // gate col 0..383
    int k = r & 127;     // k 0..127
    const float* wi = w_ih + (size_t)j * 128;
    const float* wk = W + (size_t)t * 16384 + (size_t)k * 128;
    float acc = 0.f;
#pragma unroll 4
    for (int c = 0; c < 128; ++c) acc = fmaf(wk[c], wi[c], acc);
    unsigned short x = bf16_rne(acc);
    WcT_hi[idx] = x;
    WcT_lo[idx] = bf16_rne(acc - bf16f(x));
  } else if (idx < L * per_layer + per_layer) {
    int r = idx - L * per_layer;
    float v = w_hh[r];
    unsigned short x = bf16_rne(v);
    Whh_hi[r] = x;
    Whh_lo[r] = bf16_rne(v - bf16f(x));
  }
}

// ---------------------------------------------------------------------------
// CSR build: histogram -> 2-level exclusive scan -> placement
// ---------------------------------------------------------------------------
__global__ void hist_kernel(const int* __restrict__ ei, int* __restrict__ cnt, int E) {
  int e = blockIdx.x * 256 + threadIdx.x;
  if (e < E) atomicAdd(&cnt[ei[E + e]], 1);
}

__global__ void scan1_kernel(const int* __restrict__ cnt, int* __restrict__ exscan,
                             int* __restrict__ chunk_sums, int N) {
  __shared__ int tmp[256];
  int i = blockIdx.x * 256 + threadIdx.x;
  int v = (i < N) ? cnt[i] : 0;
  tmp[threadIdx.x] = v;
  __syncthreads();
#pragma unroll
  for (int off = 1; off < 256; off <<= 1) {
    int a = (threadIdx.x >= off) ? tmp[threadIdx.x - off] : 0;
    __syncthreads();
    tmp[threadIdx.x] += a;
    __syncthreads();
  }
  if (i < N) exscan[i] = tmp[threadIdx.x] - v;
  if (threadIdx.x == 255) chunk_sums[blockIdx.x] = tmp[255];
}

__global__ void scan2_kernel(int* __restrict__ chunk_sums, int nchunk) {
  __shared__ int tmp[256];
  int v = (threadIdx.x < nchunk) ? chunk_sums[threadIdx.x] : 0;
  tmp[threadIdx.x] = v;
  __syncthreads();
#pragma unroll
  for (int off = 1; off < 256; off <<= 1) {
    int a = (threadIdx.x >= off) ? tmp[threadIdx.x - off] : 0;
    __syncthreads();
    tmp[threadIdx.x] += a;
    __syncthreads();
  }
  if (threadIdx.x < nchunk) chunk_sums[threadIdx.x] = tmp[threadIdx.x] - v;  // exclusive
}

__global__ void finalize_rowptr_kernel(const int* __restrict__ exscan,
                                       const int* __restrict__ chunk_sums,
                                       int* __restrict__ rowptr, int* __restrict__ cursor,
                                       int N, int E) {
  int i = blockIdx.x * 256 + threadIdx.x;
  if (i < N) {
    int v = exscan[i] + chunk_sums[i >> 8];
    rowptr[i] = v;
    cursor[i] = v;
  }
  if (i == N) rowptr[N] = E;
}

__global__ void place_kernel(const int* __restrict__ ei, int* __restrict__ cursor,
                             int* __restrict__ csr_src, int E) {
  int e = blockIdx.x * 256 + threadIdx.x;
  if (e >= E) return;
  int pos = atomicAdd(&cursor[ei[E + e]], 1);
  csr_src[pos] = ei[e];
}

// ---------------------------------------------------------------------------
// gather: s[node] = sum over in-edges of h[src]; write bf16 hi/lo split only.
// 128 threads per node (thread c owns feature c), 2 nodes per 256-block.
// Per edge: one coalesced 512B row read. No atomics.
// ---------------------------------------------------------------------------
__global__ __launch_bounds__(256) void gather_kernel(
    const float* __restrict__ h, const int* __restrict__ rowptr,
    const int* __restrict__ csr_src,
    unsigned short* __restrict__ s_hi, unsigned short* __restrict__ s_lo, int N) {
  int node = blockIdx.x * 2 + (threadIdx.x >> 7);
  if (node >= N) return;
  int c = threadIdx.x & 127;
  int beg = rowptr[node], end = rowptr[node + 1];
  float acc = 0.f;
  int j = beg;
  for (; j + 2 <= end; j += 2) {
    int s0 = csr_src[j];
    int s1 = csr_src[j + 1];
    float a = h[(size_t)s0 * F + c];
    float b = h[(size_t)s1 * F + c];
    acc += a;
    acc += b;
  }
  if (j < end) acc += h[(size_t)csr_src[j] * F + c];
  size_t o = (size_t)node * F + c;
  unsigned short x = bf16_rne(acc);
  s_hi[o] = x;
  s_lo[o] = bf16_rne(acc - bf16f(x));
}

// ---------------------------------------------------------------------------
// gemm_gru: per block = 32 rows x all 128 gate cols. 8 waves:
//   wave w: rowtile wr=w>>2 (16 rows), gates g0=(w&3)*32 (2 col-tiles of 16).
// For each (gatetile, part in {r,z,n}): C1 = s@Wc, C2 = h@WhhT, each via
// 3 MFMAs (hi*hi, lo*hi, hi*lo) of 16x16x32 bf16. 12 f32x4 accs per lane.
// Epilogue: GRU gates, in-place h update + fused bf16 hi/lo re-split.
// ---------------------------------------------------------------------------
__global__ __launch_bounds__(512) void gemm_gru_kernel(
    const unsigned short* __restrict__ s_hi, const unsigned short* __restrict__ s_lo,
    const unsigned short* __restrict__ h_hi, const unsigned short* __restrict__ h_lo,
    const unsigned short* __restrict__ BcT_hi, const unsigned short* __restrict__ BcT_lo,
    const unsigned short* __restrict__ BhT_hi, const unsigned short* __restrict__ BhT_lo,
    const float* __restrict__ bih, const float* __restrict__ bhh,
    float* __restrict__ h, unsigned short* __restrict__ h_hi_out,
    unsigned short* __restrict__ h_lo_out, int N) {
  const int w    = threadIdx.x >> 6;
  const int lane = threadIdx.x & 63;
  const int wr   = w >> 2;
  const int g0   = (w & 3) * 32;
  const int lrow = lane & 15;
  const int lk   = (lane >> 4) * 8;
  const int row0 = blockIdx.x * 32 + wr * 16;

  int arow = row0 + lrow;
  int arow_c = arow < N ? arow : N - 1;
  const size_t a_base = (size_t)arow_c * F + lk;

  f32x4 acc[12];
#pragma unroll
  for (int i = 0; i < 12; ++i) acc[i] = (f32x4){0.f, 0.f, 0.f, 0.f};

#pragma unroll 1
  for (int k0 = 0; k0 < 128; k0 += 32) {
    const bf16x8 a_sh = *(const bf16x8*)(s_hi + a_base + k0);
    const bf16x8 a_sl = *(const bf16x8*)(s_lo + a_base + k0);
    const bf16x8 a_hh = *(const bf16x8*)(h_hi + a_base + k0);
    const bf16x8 a_hl = *(const bf16x8*)(h_lo + a_base + k0);
#pragma unroll
    for (int t2 = 0; t2 < 2; ++t2) {
#pragma unroll
      for (int part = 0; part < 3; ++part) {
        const size_t boff = (size_t)(g0 + t2 * 16 + part * 128 + lrow) * 128 + k0 + lk;
        const int ia = (t2 * 3 + part) * 2;
        bf16x8 bh = *(const bf16x8*)(BcT_hi + boff);
        bf16x8 bl = *(const bf16x8*)(BcT_lo + boff);
        acc[ia] = __builtin_amdgcn_mfma_f32_16x16x32_bf16(a_sh, bh, acc[ia], 0, 0, 0);
        acc[ia] = __builtin_amdgcn_mfma_f32_16x16x32_bf16(a_sl, bh, acc[ia], 0, 0, 0);
        acc[ia] = __builtin_amdgcn_mfma_f32_16x16x32_bf16(a_sh, bl, acc[ia], 0, 0, 0);
        bh = *(const bf16x8*)(BhT_hi + boff);
        bl = *(const bf16x8*)(BhT_lo + boff);
        acc[ia + 1] = __builtin_amdgcn_mfma_f32_16x16x32_bf16(a_hh, bh, acc[ia + 1], 0, 0, 0);
        acc[ia + 1] = __builtin_amdgcn_mfma_f32_16x16x32_bf16(a_hl, bh, acc[ia + 1], 0, 0, 0);
        acc[ia + 1] = __builtin_amdgcn_mfma_f32_16x16x32_bf16(a_hh, bl, acc[ia + 1], 0, 0, 0);
      }
    }
  }

  // all K-loop reads of h_hi/h_lo in this block must complete before any wave
  // overwrites them (blocks only touch their own 32 rows -> in-place is safe)
  __syncthreads();

  const int rbase = row0 + (lane >> 4) * 4;
#pragma unroll
  for (int t2 = 0; t2 < 2; ++t2) {
    const int c = g0 + t2 * 16 + lrow;
    const float br  = bih[c] + bhh[c];
    const float bz  = bih[128 + c] + bhh[128 + c];
    const float bni = bih[256 + c];
    const float bnh = bhh[256 + c];
#pragma unroll
    for (int i = 0; i < 4; ++i) {
      const int r = rbase + i;
      if (r < N) {
        const float c1r = acc[(t2 * 3 + 0) * 2 + 0][i], c2r = acc[(t2 * 3 + 0) * 2 + 1][i];
        const float c1z = acc[(t2 * 3 + 1) * 2 + 0][i], c2z = acc[(t2 * 3 + 1) * 2 + 1][i];
        const float c1n = acc[(t2 * 3 + 2) * 2 + 0][i], c2n = acc[(t2 * 3 + 2) * 2 + 1][i];
        const float rr = 1.f / (1.f + __expf(-(c1r + c2r + br)));
        const float zz = 1.f / (1.f + __expf(-(c1z + c2z + bz)));
        const float nn = tanhf(c1n + bni + rr * (c2n + bnh));
        const size_t o = (size_t)r * F + c;
        const float hold = h[o];
        const float hn = (1.f - zz) * nn + zz * hold;
        h[o] = hn;
        const unsigned short x = bf16_rne(hn);
        h_hi_out[o] = x;
        h_lo_out[o] = bf16_rne(hn - bf16f(x));
      }
    }
  }
}

// ---------------------------------------------------------------------------
// final: out[n] = relu(h[n]) . lin_w + lin_b   (one wave per node)
// ---------------------------------------------------------------------------
__global__ void final_kernel(const float* __restrict__ h, const float* __restrict__ lin_w,
                             const float* __restrict__ lin_b, float* __restrict__ out, int N) {
  int n = blockIdx.x * 4 + (threadIdx.x >> 6);
  if (n >= N) return;
  int lane = threadIdx.x & 63;
  float2 v = *(const float2*)(h + (size_t)n * F + lane * 2);
  float2 wv = *(const float2*)(lin_w + lane * 2);
  float sum = fmaxf(v.x, 0.f) * wv.x + fmaxf(v.y, 0.f) * wv.y;
#pragma unroll
  for (int o = 32; o; o >>= 1) sum += __shfl_xor(sum, o, 64);
  if (lane == 0) out[n] = sum + lin_b[0];
}

// ---------------------------------------------------------------------------
extern "C" void kernel_launch(void* const* d_in, const int* in_sizes, int n_in,
                              void* d_out, int out_size, void* d_ws, size_t ws_size,
                              hipStream_t stream) {
  const float* x     = (const float*)d_in[0];
  const int*   ei    = (const int*)d_in[1];
  const float* W     = (const float*)d_in[2];
  const float* w_ih  = (const float*)d_in[3];
  const float* w_hh  = (const float*)d_in[4];
  const float* b_ih  = (const float*)d_in[5];
  const float* b_hh  = (const float*)d_in[6];
  const float* lin_w = (const float*)d_in[7];
  const float* lin_b = (const float*)d_in[8];

  const int N = in_sizes[0] / F;         // 50000
  const int E = in_sizes[1] / 2;         // 640000
  const int L = in_sizes[2] / (F * F);   // 5
  const size_t NF = (size_t)N * F;
  const int PW = 384 * 128;              // per-layer combined-weight elems

  // workspace layout
  char* p = (char*)d_ws;
  float* h = (float*)p;                   p += NF * 4;
  unsigned short* h_hi = (unsigned short*)p; p += NF * 2;
  unsigned short* h_lo = (unsigned short*)p; p += NF * 2;
  unsigned short* s_hi = (unsigned short*)p; p += NF * 2;
  unsigned short* s_lo = (unsigned short*)p; p += NF * 2;
  unsigned short* WcT_hi = (unsigned short*)p; p += (size_t)L * PW * 2;
  unsigned short* WcT_lo = (unsigned short*)p; p += (size_t)L * PW * 2;
  unsigned short* Whh_hi = (unsigned short*)p; p += PW * 2;
  unsigned short* Whh_lo = (unsigned short*)p; p += PW * 2;
  int* cnt       = (int*)p; p += (size_t)N * 4;
  int* exscan    = (int*)p; p += (size_t)N * 4;
  int* chunk     = (int*)p; p += 256 * 4;
  int* rowptr    = (int*)p; p += ((size_t)N + 1) * 4;
  int* cursor    = (int*)p; p += (size_t)N * 4;
  int* csr_src   = (int*)p; p += (size_t)E * 4;

  const int n8 = (int)(NF / 8);
  const int split_blocks = (n8 + 255) / 256;
  const int prep_blocks = (L * PW + PW + 255) / 256;
  const int edge_blocks = (E + 255) / 256;
  const int nchunk = (N + 255) / 256;
  const int gemm_blocks = (N + 31) / 32;
  const int final_blocks = (N + 3) / 4;

  // h = x (f32 copy) + hi/lo split; combined weights
  split8_kernel<<<split_blocks, 256, 0, stream>>>(x, h, h_hi, h_lo, n8);
  prep_w_kernel<<<prep_blocks, 256, 0, stream>>>(W, w_ih, w_hh, WcT_hi, WcT_lo,
                                                 Whh_hi, Whh_lo, L);

  // CSR build (once per call)
  hipMemsetAsync(cnt, 0, (size_t)N * 4, stream);
  hist_kernel<<<edge_blocks, 256, 0, stream>>>(ei, cnt, E);
  scan1_kernel<<<nchunk, 256, 0, stream>>>(cnt, exscan, chunk, N);
  scan2_kernel<<<1, 256, 0, stream>>>(chunk, nchunk);
  finalize_rowptr_kernel<<<(N + 256) / 256, 256, 0, stream>>>(exscan, chunk, rowptr, cursor, N, E);
  place_kernel<<<edge_blocks, 256, 0, stream>>>(ei, cursor, csr_src, E);

  for (int t = 0; t < L; ++t) {
    gather_kernel<<<(N + 1) / 2, 256, 0, stream>>>(h, rowptr, csr_src, s_hi, s_lo, N);
    gemm_gru_kernel<<<gemm_blocks, 512, 0, stream>>>(
        s_hi, s_lo, h_hi, h_lo,
        WcT_hi + (size_t)t * PW, WcT_lo + (size_t)t * PW, Whh_hi, Whh_lo,
        b_ih, b_hh, h, h_hi, h_lo, N);
  }

  final_kernel<<<final_blocks, 256, 0, stream>>>(h, lin_w, lin_b, (float*)d_out, N);
}

// Round 3
// 772.656 us; speedup vs baseline: 8.3501x; 1.8615x over previous
//
#include <hip/hip_runtime.h>

typedef float f32x4 __attribute__((ext_vector_type(4)));
typedef __bf16 bf16x8 __attribute__((ext_vector_type(8)));
typedef unsigned short u16x8 __attribute__((ext_vector_type(8)));

#define F 128

__device__ __forceinline__ unsigned short bf16_rne(float f) {
  unsigned u = __float_as_uint(f);
  u += 0x7FFFu + ((u >> 16) & 1u);
  return (unsigned short)(u >> 16);
}
__device__ __forceinline__ float bf16f(unsigned short s) {
  return __uint_as_float((unsigned)s << 16);
}

// ---------------------------------------------------------------------------
// split8: read 8 f32, write bf16 hi/lo pairs
// ---------------------------------------------------------------------------
__global__ void split8_kernel(const float* __restrict__ in,
                              unsigned short* __restrict__ hi, unsigned short* __restrict__ lo,
                              int n8) {
  int i = blockIdx.x * 256 + threadIdx.x;
  if (i >= n8) return;
  const float4* p = (const float4*)in + 2 * (size_t)i;
  float4 a = p[0], b = p[1];
  float v[8] = {a.x, a.y, a.z, a.w, b.x, b.y, b.z, b.w};
  u16x8 vh, vl;
#pragma unroll
  for (int e = 0; e < 8; ++e) {
    unsigned short x = bf16_rne(v[e]);
    vh[e] = x;
    vl[e] = bf16_rne(v[e] - bf16f(x));
  }
  *(u16x8*)(hi + 8 * (size_t)i) = vh;
  *(u16x8*)(lo + 8 * (size_t)i) = vl;
}

// ---------------------------------------------------------------------------
// Fragment-packed B layout:
//   frag f = ks*24 + j/16  (ks = k/32), holds B[j0:j0+16][k0:k0+32] as
//   packed[f*512 + lane*8 + e] = B[j0+(lane&15)][k0 + (lane>>4)*8 + e]
//   -> each MFMA B-fragment load is one coalesced 1KB wave burst.
// ---------------------------------------------------------------------------
__device__ __forceinline__ int pidx(int j, int k) {
  int ks = k >> 5;
  int lane = (j & 15) | (((k >> 3) & 3) << 4);
  return (ks * 24 + (j >> 4)) * 512 + lane * 8 + (k & 7);
}

// prep_w: Wc[t][j][k] = dot(W[t][k][:], w_ih[j][:]); Whh[j][k] = w_hh[j][k];
// both written as bf16 hi/lo pairs in fragment-packed layout.
__global__ void prep_w_kernel(const float* __restrict__ W, const float* __restrict__ w_ih,
                              const float* __restrict__ w_hh,
                              unsigned short* __restrict__ WcT_hi, unsigned short* __restrict__ WcT_lo,
                              unsigned short* __restrict__ Whh_hi, unsigned short* __restrict__ Whh_lo,
                              int L) {
  int idx = blockIdx.x * 256 + threadIdx.x;
  const int per_layer = 384 * 128;
  if (idx < L * per_layer) {
    int t = idx / per_layer;
    int r = idx - t * per_layer;
    int j = r >> 7;      // gate col 0..383
    int k = r & 127;     // k 0..127
    const float* wi = w_ih + (size_t)j * 128;
    const float* wk = W + (size_t)t * 16384 + (size_t)k * 128;
    float acc = 0.f;
#pragma unroll 4
    for (int c = 0; c < 128; ++c) acc = fmaf(wk[c], wi[c], acc);
    unsigned short x = bf16_rne(acc);
    int p = t * per_layer + pidx(j, k);
    WcT_hi[p] = x;
    WcT_lo[p] = bf16_rne(acc - bf16f(x));
  } else if (idx < L * per_layer + per_layer) {
    int r = idx - L * per_layer;
    int j = r >> 7, k = r & 127;
    float v = w_hh[r];
    unsigned short x = bf16_rne(v);
    int p = pidx(j, k);
    Whh_hi[p] = x;
    Whh_lo[p] = bf16_rne(v - bf16f(x));
  }
}

// ---------------------------------------------------------------------------
// CSR build: histogram -> 2-level exclusive scan -> placement
// ---------------------------------------------------------------------------
__global__ void hist_kernel(const int* __restrict__ ei, int* __restrict__ cnt, int E) {
  int e = blockIdx.x * 256 + threadIdx.x;
  if (e < E) atomicAdd(&cnt[ei[E + e]], 1);
}

__global__ void scan1_kernel(const int* __restrict__ cnt, int* __restrict__ exscan,
                             int* __restrict__ chunk_sums, int N) {
  __shared__ int tmp[256];
  int i = blockIdx.x * 256 + threadIdx.x;
  int v = (i < N) ? cnt[i] : 0;
  tmp[threadIdx.x] = v;
  __syncthreads();
#pragma unroll
  for (int off = 1; off < 256; off <<= 1) {
    int a = (threadIdx.x >= off) ? tmp[threadIdx.x - off] : 0;
    __syncthreads();
    tmp[threadIdx.x] += a;
    __syncthreads();
  }
  if (i < N) exscan[i] = tmp[threadIdx.x] - v;
  if (threadIdx.x == 255) chunk_sums[blockIdx.x] = tmp[255];
}

__global__ void scan2_kernel(int* __restrict__ chunk_sums, int nchunk) {
  __shared__ int tmp[256];
  int v = (threadIdx.x < nchunk) ? chunk_sums[threadIdx.x] : 0;
  tmp[threadIdx.x] = v;
  __syncthreads();
#pragma unroll
  for (int off = 1; off < 256; off <<= 1) {
    int a = (threadIdx.x >= off) ? tmp[threadIdx.x - off] : 0;
    __syncthreads();
    tmp[threadIdx.x] += a;
    __syncthreads();
  }
  if (threadIdx.x < nchunk) chunk_sums[threadIdx.x] = tmp[threadIdx.x] - v;  // exclusive
}

__global__ void finalize_rowptr_kernel(const int* __restrict__ exscan,
                                       const int* __restrict__ chunk_sums,
                                       int* __restrict__ rowptr, int* __restrict__ cursor,
                                       int N, int E) {
  int i = blockIdx.x * 256 + threadIdx.x;
  if (i < N) {
    int v = exscan[i] + chunk_sums[i >> 8];
    rowptr[i] = v;
    cursor[i] = v;
  }
  if (i == N) rowptr[N] = E;
}

__global__ void place_kernel(const int* __restrict__ ei, int* __restrict__ cursor,
                             int* __restrict__ csr_src, int E) {
  int e = blockIdx.x * 256 + threadIdx.x;
  if (e >= E) return;
  int pos = atomicAdd(&cursor[ei[E + e]], 1);
  csr_src[pos] = ei[e];
}

// ---------------------------------------------------------------------------
// gather: s[node][:] = sum over in-edges of (h_hi+h_lo)[src][:], re-split to
// bf16 hi/lo. 64 threads per node, thread d owns features {2d,2d+1} via u32
// loads; 4-edge unroll for memory-level parallelism. No atomics.
// ---------------------------------------------------------------------------
__global__ __launch_bounds__(256) void gather_kernel(
    const unsigned* __restrict__ hh, const unsigned* __restrict__ hl,
    const int* __restrict__ rowptr, const int* __restrict__ csr_src,
    unsigned* __restrict__ shi, unsigned* __restrict__ slo, int N) {
  int node = blockIdx.x * 4 + (threadIdx.x >> 6);
  if (node >= N) return;
  int d = threadIdx.x & 63;
  int beg = rowptr[node], end = rowptr[node + 1];
  float a0 = 0.f, a1 = 0.f;
  int j = beg;
  for (; j + 4 <= end; j += 4) {
    int s0 = csr_src[j], s1 = csr_src[j + 1], s2 = csr_src[j + 2], s3 = csr_src[j + 3];
    unsigned h0 = hh[(size_t)s0 * 64 + d], l0 = hl[(size_t)s0 * 64 + d];
    unsigned h1 = hh[(size_t)s1 * 64 + d], l1 = hl[(size_t)s1 * 64 + d];
    unsigned h2 = hh[(size_t)s2 * 64 + d], l2 = hl[(size_t)s2 * 64 + d];
    unsigned h3 = hh[(size_t)s3 * 64 + d], l3 = hl[(size_t)s3 * 64 + d];
    a0 += bf16f(h0 & 0xffff) + bf16f(l0 & 0xffff);
    a1 += bf16f(h0 >> 16) + bf16f(l0 >> 16);
    a0 += bf16f(h1 & 0xffff) + bf16f(l1 & 0xffff);
    a1 += bf16f(h1 >> 16) + bf16f(l1 >> 16);
    a0 += bf16f(h2 & 0xffff) + bf16f(l2 & 0xffff);
    a1 += bf16f(h2 >> 16) + bf16f(l2 >> 16);
    a0 += bf16f(h3 & 0xffff) + bf16f(l3 & 0xffff);
    a1 += bf16f(h3 >> 16) + bf16f(l3 >> 16);
  }
  for (; j < end; ++j) {
    int s0 = csr_src[j];
    unsigned h0 = hh[(size_t)s0 * 64 + d], l0 = hl[(size_t)s0 * 64 + d];
    a0 += bf16f(h0 & 0xffff) + bf16f(l0 & 0xffff);
    a1 += bf16f(h0 >> 16) + bf16f(l0 >> 16);
  }
  unsigned short x0 = bf16_rne(a0), x1 = bf16_rne(a1);
  unsigned short y0 = bf16_rne(a0 - bf16f(x0)), y1 = bf16_rne(a1 - bf16f(x1));
  size_t o = (size_t)node * 64 + d;
  shi[o] = (unsigned)x0 | ((unsigned)x1 << 16);
  slo[o] = (unsigned)y0 | ((unsigned)y1 << 16);
}

// ---------------------------------------------------------------------------
// gemm_gru: block = 64 rows x all 128 gate cols. 8 waves:
//   wave w: row-half rh=w>>2 (32 rows = 2 row-tiles), gates g0=(w&3)*32.
// Per k-step: 24 packed-coalesced B loads + 8 A loads, 72 MFMAs.
// 24 f32x4 accs/lane; launch_bounds(512,2) -> <=256 VGPR so all loads of a
// k-step stay in flight. Epilogue: GRU gates, h (hi/lo pair) updated in place.
// ---------------------------------------------------------------------------
__global__ __launch_bounds__(512, 2) void gemm_gru_kernel(
    const unsigned short* __restrict__ s_hi, const unsigned short* __restrict__ s_lo,
    const unsigned short* __restrict__ h_hi, const unsigned short* __restrict__ h_lo,
    const unsigned short* __restrict__ Bc_hi, const unsigned short* __restrict__ Bc_lo,
    const unsigned short* __restrict__ Bh_hi, const unsigned short* __restrict__ Bh_lo,
    const float* __restrict__ bih, const float* __restrict__ bhh,
    unsigned short* __restrict__ h_hi_out, unsigned short* __restrict__ h_lo_out, int N) {
  const int w    = threadIdx.x >> 6;
  const int lane = threadIdx.x & 63;
  const int rh   = w >> 2;
  const int g0   = (w & 3) * 32;
  const int lrow = lane & 15;
  const int row0 = blockIdx.x * 64 + rh * 32;
  const int lane8 = lane * 8;

  size_t a_base[2];
#pragma unroll
  for (int t = 0; t < 2; ++t) {
    int ar = row0 + t * 16 + lrow;
    if (ar >= N) ar = N - 1;
    a_base[t] = (size_t)ar * F + (lane >> 4) * 8;
  }

  f32x4 acc[24];  // [(t*6 + t2*3 + part)*2 + cc]
#pragma unroll
  for (int i = 0; i < 24; ++i) acc[i] = (f32x4){0.f, 0.f, 0.f, 0.f};

#pragma unroll
  for (int ks = 0; ks < 4; ++ks) {
    bf16x8 bch[6], bcl[6], bhh_[6], bhl[6];
#pragma unroll
    for (int g = 0; g < 6; ++g) {
      const int cb = g0 + (g / 3) * 16 + (g % 3) * 128;   // compile-time per g
      const size_t pf = ((size_t)(ks * 24 + (cb >> 4)) * 512) + lane8;
      bch[g]  = *(const bf16x8*)(Bc_hi + pf);
      bcl[g]  = *(const bf16x8*)(Bc_lo + pf);
      bhh_[g] = *(const bf16x8*)(Bh_hi + pf);
      bhl[g]  = *(const bf16x8*)(Bh_lo + pf);
    }
    bf16x8 ash[2], asl[2], ahh[2], ahl[2];
#pragma unroll
    for (int t = 0; t < 2; ++t) {
      const size_t ao = a_base[t] + ks * 32;
      ash[t] = *(const bf16x8*)(s_hi + ao);
      asl[t] = *(const bf16x8*)(s_lo + ao);
      ahh[t] = *(const bf16x8*)(h_hi + ao);
      ahl[t] = *(const bf16x8*)(h_lo + ao);
    }
#pragma unroll
    for (int t = 0; t < 2; ++t) {
#pragma unroll
      for (int g = 0; g < 6; ++g) {
        const int ia = (t * 6 + g) * 2;
        acc[ia] = __builtin_amdgcn_mfma_f32_16x16x32_bf16(ash[t], bch[g], acc[ia], 0, 0, 0);
        acc[ia] = __builtin_amdgcn_mfma_f32_16x16x32_bf16(asl[t], bch[g], acc[ia], 0, 0, 0);
        acc[ia] = __builtin_amdgcn_mfma_f32_16x16x32_bf16(ash[t], bcl[g], acc[ia], 0, 0, 0);
        acc[ia + 1] = __builtin_amdgcn_mfma_f32_16x16x32_bf16(ahh[t], bhh_[g], acc[ia + 1], 0, 0, 0);
        acc[ia + 1] = __builtin_amdgcn_mfma_f32_16x16x32_bf16(ahl[t], bhh_[g], acc[ia + 1], 0, 0, 0);
        acc[ia + 1] = __builtin_amdgcn_mfma_f32_16x16x32_bf16(ahh[t], bhl[g], acc[ia + 1], 0, 0, 0);
      }
    }
  }

  // all A-reads of h_hi/h_lo in this block must finish before in-place update
  __syncthreads();

#pragma unroll
  for (int t = 0; t < 2; ++t) {
    const int rbase = row0 + t * 16 + (lane >> 4) * 4;
#pragma unroll
    for (int t2 = 0; t2 < 2; ++t2) {
      const int c = g0 + t2 * 16 + lrow;
      const float br  = bih[c] + bhh[c];
      const float bz  = bih[128 + c] + bhh[128 + c];
      const float bni = bih[256 + c];
      const float bnh = bhh[256 + c];
#pragma unroll
      for (int i = 0; i < 4; ++i) {
        const int r = rbase + i;
        if (r < N) {
          const int b0 = (t * 6 + t2 * 3) * 2;
          const float c1r = acc[b0 + 0][i], c2r = acc[b0 + 1][i];
          const float c1z = acc[b0 + 2][i], c2z = acc[b0 + 3][i];
          const float c1n = acc[b0 + 4][i], c2n = acc[b0 + 5][i];
          const float rr = 1.f / (1.f + __expf(-(c1r + c2r + br)));
          const float zz = 1.f / (1.f + __expf(-(c1z + c2z + bz)));
          const float nn = tanhf(c1n + bni + rr * (c2n + bnh));
          const size_t o = (size_t)r * F + c;
          const float hold = bf16f(h_hi_out[o]) + bf16f(h_lo_out[o]);
          const float hn = (1.f - zz) * nn + zz * hold;
          const unsigned short x = bf16_rne(hn);
          h_hi_out[o] = x;
          h_lo_out[o] = bf16_rne(hn - bf16f(x));
        }
      }
    }
  }
}

// ---------------------------------------------------------------------------
// final: out[n] = relu(h[n]) . lin_w + lin_b   (one wave per node, h = hi+lo)
// ---------------------------------------------------------------------------
__global__ void final_kernel(const unsigned* __restrict__ hh, const unsigned* __restrict__ hl,
                             const float* __restrict__ lin_w,
                             const float* __restrict__ lin_b, float* __restrict__ out, int N) {
  int n = blockIdx.x * 4 + (threadIdx.x >> 6);
  if (n >= N) return;
  int lane = threadIdx.x & 63;
  unsigned wh = hh[(size_t)n * 64 + lane], wl = hl[(size_t)n * 64 + lane];
  float v0 = bf16f(wh & 0xffff) + bf16f(wl & 0xffff);
  float v1 = bf16f(wh >> 16) + bf16f(wl >> 16);
  float2 wv = *(const float2*)(lin_w + lane * 2);
  float sum = fmaxf(v0, 0.f) * wv.x + fmaxf(v1, 0.f) * wv.y;
#pragma unroll
  for (int o = 32; o; o >>= 1) sum += __shfl_xor(sum, o, 64);
  if (lane == 0) out[n] = sum + lin_b[0];
}

// ---------------------------------------------------------------------------
extern "C" void kernel_launch(void* const* d_in, const int* in_sizes, int n_in,
                              void* d_out, int out_size, void* d_ws, size_t ws_size,
                              hipStream_t stream) {
  const float* x     = (const float*)d_in[0];
  const int*   ei    = (const int*)d_in[1];
  const float* W     = (const float*)d_in[2];
  const float* w_ih  = (const float*)d_in[3];
  const float* w_hh  = (const float*)d_in[4];
  const float* b_ih  = (const float*)d_in[5];
  const float* b_hh  = (const float*)d_in[6];
  const float* lin_w = (const float*)d_in[7];
  const float* lin_b = (const float*)d_in[8];

  const int N = in_sizes[0] / F;         // 50000
  const int E = in_sizes[1] / 2;         // 640000
  const int L = in_sizes[2] / (F * F);   // 5
  const size_t NF = (size_t)N * F;
  const int PW = 384 * 128;              // per-layer combined-weight elems

  // workspace layout
  char* p = (char*)d_ws;
  unsigned short* h_hi = (unsigned short*)p; p += NF * 2;
  unsigned short* h_lo = (unsigned short*)p; p += NF * 2;
  unsigned short* s_hi = (unsigned short*)p; p += NF * 2;
  unsigned short* s_lo = (unsigned short*)p; p += NF * 2;
  unsigned short* WcT_hi = (unsigned short*)p; p += (size_t)L * PW * 2;
  unsigned short* WcT_lo = (unsigned short*)p; p += (size_t)L * PW * 2;
  unsigned short* Whh_hi = (unsigned short*)p; p += PW * 2;
  unsigned short* Whh_lo = (unsigned short*)p; p += PW * 2;
  int* cnt       = (int*)p; p += (size_t)N * 4;
  int* exscan    = (int*)p; p += (size_t)N * 4;
  int* chunk     = (int*)p; p += 256 * 4;
  int* rowptr    = (int*)p; p += ((size_t)N + 1) * 4;
  int* cursor    = (int*)p; p += (size_t)N * 4;
  int* csr_src   = (int*)p; p += (size_t)E * 4;

  const int n8 = (int)(NF / 8);
  const int split_blocks = (n8 + 255) / 256;
  const int prep_blocks = (L * PW + PW + 255) / 256;
  const int edge_blocks = (E + 255) / 256;
  const int nchunk = (N + 255) / 256;
  const int gemm_blocks = (N + 63) / 64;
  const int node4_blocks = (N + 3) / 4;

  // h = split(x); combined weights (fragment-packed)
  split8_kernel<<<split_blocks, 256, 0, stream>>>(x, h_hi, h_lo, n8);
  prep_w_kernel<<<prep_blocks, 256, 0, stream>>>(W, w_ih, w_hh, WcT_hi, WcT_lo,
                                                 Whh_hi, Whh_lo, L);

  // CSR build (once per call)
  hipMemsetAsync(cnt, 0, (size_t)N * 4, stream);
  hist_kernel<<<edge_blocks, 256, 0, stream>>>(ei, cnt, E);
  scan1_kernel<<<nchunk, 256, 0, stream>>>(cnt, exscan, chunk, N);
  scan2_kernel<<<1, 256, 0, stream>>>(chunk, nchunk);
  finalize_rowptr_kernel<<<(N + 256) / 256, 256, 0, stream>>>(exscan, chunk, rowptr, cursor, N, E);
  place_kernel<<<edge_blocks, 256, 0, stream>>>(ei, cursor, csr_src, E);

  for (int t = 0; t < L; ++t) {
    gather_kernel<<<node4_blocks, 256, 0, stream>>>(
        (const unsigned*)h_hi, (const unsigned*)h_lo, rowptr, csr_src,
        (unsigned*)s_hi, (unsigned*)s_lo, N);
    gemm_gru_kernel<<<gemm_blocks, 512, 0, stream>>>(
        s_hi, s_lo, h_hi, h_lo,
        WcT_hi + (size_t)t * PW, WcT_lo + (size_t)t * PW, Whh_hi, Whh_lo,
        b_ih, b_hh, h_hi, h_lo, N);
  }

  final_kernel<<<node4_blocks, 256, 0, stream>>>(
      (const unsigned*)h_hi, (const unsigned*)h_lo, lin_w, lin_b, (float*)d_out, N);
}